// Round 16
// baseline (310.433 us; speedup 1.0000x reference)
//
#include <hip/hip_runtime.h>
#include <math.h>

#define N_NODES 50000
#define N_EDGES 800000
#define D_IN 512
#define D_LAT 256
#define D_EMB 64
#define NEG_SLOPE 0.2f

typedef __attribute__((ext_vector_type(8))) short bf16x8;
typedef __attribute__((ext_vector_type(8))) unsigned short u16x8;
typedef __attribute__((ext_vector_type(4))) float f32x4;

__device__ __forceinline__ ushort f2b(float f) {
  union { float f; unsigned u; } v; v.f = f;
  return (ushort)((v.u + 0x7fffu + ((v.u >> 16) & 1u)) >> 16);
}
__device__ __forceinline__ float b2f(ushort h) {
  union { unsigned u; float f; } v; v.u = ((unsigned)h) << 16;
  return v.f;
}

// ---------------------------------------------------------------------------
// bf16 MFMA GEMM: C[M,N] = A[M,K] @ B[N,K]^T  (row-major).
// AF32=1: A f32, staged regs+cvt+ds_write (linear LDS layout).
// AF32=0: A bf16 via global_load_lds w16.  ELU: fused elu epilogue.
// LOGIT=1 (requires grid.x==1, BN==N): also emit als/ald = C·a_src / C·a_dst.
// LDS tiles [rows][32] (64B rows): fragment reads tile 1KB.
// ---------------------------------------------------------------------------
template <int BM, int BN, int WR, int WC, int AF32, int WF32, int WBF16,
          int ELU, int LOGIT>
__global__ __launch_bounds__(WR * WC * 64) void gemm_mfma(
    const void* __restrict__ Aptr, const ushort* __restrict__ B,
    float* __restrict__ Cf, ushort* __restrict__ Cb, int M, int N, int K,
    const float* __restrict__ a_src, const float* __restrict__ a_dst,
    float* __restrict__ als, float* __restrict__ ald) {
  constexpr int BK = 32;
  constexpr int WTM = BM / WR, WTN = BN / WC;
  constexpr int FM = WTM / 16, FN = WTN / 16;
  constexpr int NT = WR * WC * 64;
  constexpr int AIT = (BM * BK * 2) / (NT * 16);
  constexpr int BIT_ = (BN * BK * 2) / (NT * 16);
  __shared__ ushort As[BM][BK];
  __shared__ ushort Bs[BN][BK];
  const int tid = threadIdx.x, lane = tid & 63, wid = tid >> 6;
  const int wr = wid / WC, wc = wid % WC;
  const int bm = blockIdx.y * BM, bn = blockIdx.x * BN;
  f32x4 acc[FM][FN] = {};

  for (int k0 = 0; k0 < K; k0 += BK) {
    if constexpr (AF32) {
      const float* Af = (const float*)Aptr;
#pragma unroll
      for (int it = 0; it < AIT; ++it) {
        int off = it * (NT * 16) + tid * 16;  // byte offset in bf16 tile
        int row = off >> 6;                   // 64 B per LDS row
        int ecol = (off & 63) >> 1;           // element col (x8)
        int grow = bm + row; grow = grow < M ? grow : (M - 1);
        const float* g = Af + (size_t)grow * K + k0 + ecol;
        float4 f0 = *(const float4*)g;
        float4 f1 = *(const float4*)(g + 4);
        u16x8 hb;
        hb[0] = f2b(f0.x); hb[1] = f2b(f0.y); hb[2] = f2b(f0.z); hb[3] = f2b(f0.w);
        hb[4] = f2b(f1.x); hb[5] = f2b(f1.y); hb[6] = f2b(f1.z); hb[7] = f2b(f1.w);
        *(u16x8*)((char*)&As[0][0] + off) = hb;
      }
    } else {
      const ushort* Ab = (const ushort*)Aptr;
#pragma unroll
      for (int it = 0; it < AIT; ++it) {
        int off = it * (NT * 16) + tid * 16;
        int row = off >> 6;
        int grow = bm + row; grow = grow < M ? grow : (M - 1);
        const ushort* g = Ab + (size_t)grow * K + k0 + ((off & 63) >> 1);
        __builtin_amdgcn_global_load_lds(
            (const __attribute__((address_space(1))) void*)g,
            (__attribute__((address_space(3))) void*)((char*)&As[0][0] + off),
            16, 0, 0);
      }
    }
#pragma unroll
    for (int it = 0; it < BIT_; ++it) {
      int off = it * (NT * 16) + tid * 16;
      int row = off >> 6;
      const ushort* g = B + (size_t)(bn + row) * K + k0 + ((off & 63) >> 1);
      __builtin_amdgcn_global_load_lds(
          (const __attribute__((address_space(1))) void*)g,
          (__attribute__((address_space(3))) void*)((char*)&Bs[0][0] + off),
          16, 0, 0);
    }
    __syncthreads();
    const int kb = (lane >> 4) * 8, rl = lane & 15;
    bf16x8 af[FM], bfr[FN];
#pragma unroll
    for (int i = 0; i < FM; ++i)
      af[i] = *(const bf16x8*)&As[wr * WTM + i * 16 + rl][kb];
#pragma unroll
    for (int j = 0; j < FN; ++j)
      bfr[j] = *(const bf16x8*)&Bs[wc * WTN + j * 16 + rl][kb];
#pragma unroll
    for (int i = 0; i < FM; ++i)
#pragma unroll
      for (int j = 0; j < FN; ++j)
        acc[i][j] = __builtin_amdgcn_mfma_f32_16x16x32_bf16(af[i], bfr[j],
                                                            acc[i][j], 0, 0, 0);
    __syncthreads();
  }
  // epilogue: C/D layout col=lane&15, row=(lane>>4)*4+reg (m89-verified)
  const int cl = lane & 15, rg = (lane >> 4) * 4;
#pragma unroll
  for (int i = 0; i < FM; ++i)
#pragma unroll
    for (int j = 0; j < FN; ++j)
#pragma unroll
      for (int r = 0; r < 4; ++r) {
        int grow = bm + wr * WTM + i * 16 + rg + r;
        if (grow >= M) continue;
        int gcol = bn + wc * WTN + j * 16 + cl;
        float v = acc[i][j][r];
        if (ELU) v = v > 0.f ? v : __expf(v) - 1.f;
        if (WF32) Cf[(size_t)grow * N + gcol] = v;
        if (WBF16) Cb[(size_t)grow * N + gcol] = f2b(v);
      }
  if constexpr (LOGIT) {
    __shared__ float alsP[BM], aldP[BM];
    for (int t = tid; t < BM; t += NT) { alsP[t] = 0.f; aldP[t] = 0.f; }
    __syncthreads();
    float asv[FN], adv[FN];
#pragma unroll
    for (int j = 0; j < FN; ++j) {
      int col = bn + wc * WTN + j * 16 + cl;
      asv[j] = a_src[col];
      adv[j] = a_dst[col];
    }
#pragma unroll
    for (int i = 0; i < FM; ++i)
#pragma unroll
      for (int r = 0; r < 4; ++r) {
        float s = 0.f, d = 0.f;
#pragma unroll
        for (int j = 0; j < FN; ++j) {
          s += acc[i][j][r] * asv[j];
          d += acc[i][j][r] * adv[j];
        }
#pragma unroll
        for (int off = 1; off < 16; off <<= 1) {
          s += __shfl_xor(s, off, 64);
          d += __shfl_xor(d, off, 64);
        }
        if (cl == 0) {
          int row = wr * WTM + i * 16 + rg + r;
          atomicAdd(&alsP[row], s);
          atomicAdd(&aldP[row], d);
        }
      }
    __syncthreads();
    for (int t = tid; t < BM; t += NT) {
      int gr = bm + t;
      if (gr < M) { als[gr] = alsP[t]; ald[gr] = aldP[t]; }
    }
  }
}

// weights conv (i < 512*256) + edge histogram (i < N_EDGES), one pass
__global__ __launch_bounds__(256) void conv_weights_hist(
    const float* __restrict__ W1, const float* __restrict__ W2,
    ushort* __restrict__ W1b, ushort* __restrict__ W1tb,
    ushort* __restrict__ W2b, ushort* __restrict__ W2tb,
    const int* __restrict__ dst, int* __restrict__ counts) {
  int i = blockIdx.x * blockDim.x + threadIdx.x;
  if (i < D_IN * D_LAT) {
    ushort b = f2b(W1[i]);
    int r = i / D_LAT, c = i % D_LAT;
    W1b[i] = b;
    W1tb[(size_t)c * D_IN + r] = b;
  }
  if (i < D_LAT * D_EMB) {
    ushort b = f2b(W2[i]);
    int r = i / D_EMB, c = i % D_EMB;
    W2b[i] = b;
    W2tb[(size_t)c * D_LAT + r] = b;
  }
  if (i < N_EDGES) atomicAdd(&counts[dst[i]], 1);
}

// --------- hierarchical exclusive scan (2-phase; consumers add bsum) -------
#define SCAN_NBLK ((N_NODES + 511) / 512)

__global__ __launch_bounds__(512) void scan_phase1(
    const int* __restrict__ counts, int* __restrict__ rowptr,
    int* __restrict__ bsum) {
  __shared__ int wsum[9];
  int idx = blockIdx.x * 512 + threadIdx.x;
  int lane = threadIdx.x & 63, wv = threadIdx.x >> 6;
  int c = (idx < N_NODES) ? counts[idx] : 0;
  int v = c;
#pragma unroll
  for (int off = 1; off < 64; off <<= 1) {
    int t = __shfl_up(v, off, 64);
    if (lane >= off) v += t;
  }
  if (lane == 63) wsum[wv] = v;
  __syncthreads();
  if (threadIdx.x == 0) {
    int r = 0;
    for (int i = 0; i < 8; i++) { int t = wsum[i]; wsum[i] = r; r += t; }
    bsum[blockIdx.x] = r;
  }
  __syncthreads();
  if (idx < N_NODES) rowptr[idx] = wsum[wv] + v - c;  // block-local exclusive
}

__global__ __launch_bounds__(128) void scan_phase2(int* __restrict__ bsum) {
  __shared__ int s[128];
  int tid = threadIdx.x;
  int v = (tid < SCAN_NBLK) ? bsum[tid] : 0;
  s[tid] = v;
  __syncthreads();
  for (int off = 1; off < 128; off <<= 1) {
    int t = (tid >= off) ? s[tid - off] : 0;
    __syncthreads();
    s[tid] += t;
    __syncthreads();
  }
  if (tid < SCAN_NBLK) bsum[tid] = s[tid] - v;  // exclusive
}

__device__ __forceinline__ int grp(const int* rowptr, const int* bsum,
                                   int idx) {
  return rowptr[idx] + bsum[idx >> 9];
}
__device__ __forceinline__ int grp_end(const int* rowptr, const int* bsum,
                                       int node) {
  return (node + 1 < N_NODES) ? rowptr[node + 1] + bsum[(node + 1) >> 9]
                              : N_EDGES;
}

// bucket edges; exp(leaky_relu(logit)) computed ONCE here; segment
// denominator accumulated via f32 atomics (avg 16-way contention).
__global__ void scatter_kernel(const int* __restrict__ src,
                               const int* __restrict__ dst,
                               const float* __restrict__ als,
                               const float* __restrict__ ald,
                               const int* __restrict__ rowptr,
                               const int* __restrict__ bsum,
                               int* __restrict__ fillArr,
                               int* __restrict__ ssrc,
                               float* __restrict__ sExp,
                               float* __restrict__ sumE) {
  int e = blockIdx.x * blockDim.x + threadIdx.x;
  if (e >= N_EDGES) return;
  int s = src[e], d = dst[e];
  int pos = grp(rowptr, bsum, d) + atomicAdd(&fillArr[d], 1);
  float x = als[s] + ald[d];
  x = (x > 0.f) ? x : NEG_SLOPE * x;
  float ev = __expf(x);  // fixed-shift softmax: logits bounded ~|8|, f32-safe
  sExp[pos] = ev;
  ssrc[pos] = s;
  atomicAdd(&sumE[d], ev);
}

// agg1: single gather pass; weights sExp[e] precomputed, denominator from
// sumE. Half-wave per edge (32 lanes x ushort8 = 512B row), 4 edges in
// flight; normalize + elu at the end.
__global__ __launch_bounds__(256) void agg_bf16_sm(
    const ushort* __restrict__ feat, const int* __restrict__ rowptr,
    const int* __restrict__ bsum, const int* __restrict__ ssrc,
    const float* __restrict__ sExp, const float* __restrict__ sumE,
    ushort* __restrict__ out) {
  int wave = threadIdx.x >> 6, lane = threadIdx.x & 63;
  int node = blockIdx.x * 4 + wave;
  if (node >= N_NODES) return;
  int beg = grp(rowptr, bsum, node), end = grp_end(rowptr, bsum, node);
  float se = sumE[node];
  float inv = (se > 0.f) ? 1.f / se : 0.f;

  int half = lane >> 5, hl = lane & 31;
  float acc[8] = {};
  int e = beg + half;
  for (; e + 6 < end; e += 8) {  // 4 edges per half-wave in flight
    int s0 = ssrc[e], s1 = ssrc[e + 2], s2 = ssrc[e + 4], s3 = ssrc[e + 6];
    float e0 = sExp[e], e1 = sExp[e + 2], e2 = sExp[e + 4], e3 = sExp[e + 6];
    u16x8 h0 = *(const u16x8*)(feat + (size_t)s0 * D_LAT + hl * 8);
    u16x8 h1 = *(const u16x8*)(feat + (size_t)s1 * D_LAT + hl * 8);
    u16x8 h2 = *(const u16x8*)(feat + (size_t)s2 * D_LAT + hl * 8);
    u16x8 h3 = *(const u16x8*)(feat + (size_t)s3 * D_LAT + hl * 8);
#pragma unroll
    for (int q = 0; q < 8; q++) acc[q] += e0 * b2f(h0[q]);
#pragma unroll
    for (int q = 0; q < 8; q++) acc[q] += e1 * b2f(h1[q]);
#pragma unroll
    for (int q = 0; q < 8; q++) acc[q] += e2 * b2f(h2[q]);
#pragma unroll
    for (int q = 0; q < 8; q++) acc[q] += e3 * b2f(h3[q]);
  }
  for (; e < end; e += 2) {
    float ev = sExp[e];
    int s2 = ssrc[e];
    u16x8 h = *(const u16x8*)(feat + (size_t)s2 * D_LAT + hl * 8);
#pragma unroll
    for (int q = 0; q < 8; q++) acc[q] += ev * b2f(h[q]);
  }
#pragma unroll
  for (int q = 0; q < 8; q++) acc[q] += __shfl_xor(acc[q], 32, 64);
  if (half == 0) {
    u16x8 o;
#pragma unroll
    for (int q = 0; q < 8; q++) {
      float v = acc[q] * inv;
      o[q] = f2b(v > 0.f ? v : __expf(v) - 1.f);
    }
    *(u16x8*)(out + (size_t)node * D_LAT + hl * 8) = o;
  }
}

// weighted gather over 64-dim bf16 rows (no elu — fused into next GEMM).
// One wave per node; quarter-waves (16 lanes x ushort4 = 128B row), 2-unroll.
__global__ __launch_bounds__(256) void agg_emb(
    const ushort* __restrict__ feat, const int* __restrict__ rowptr,
    const int* __restrict__ bsum, const int* __restrict__ ssrc,
    const float* __restrict__ sExp, const float* __restrict__ sumE,
    ushort* __restrict__ out) {
  int wave = threadIdx.x >> 6, lane = threadIdx.x & 63;
  int node = blockIdx.x * 4 + wave;
  if (node >= N_NODES) return;
  int beg = grp(rowptr, bsum, node), end = grp_end(rowptr, bsum, node);
  int q = lane >> 4, ql = lane & 15;
  float acc[4] = {};
  int e = beg + q;
  for (; e + 4 < end; e += 8) {  // 2 edges per quarter-wave in flight
    float a0 = sExp[e], a1 = sExp[e + 4];
    int s0 = ssrc[e], s1 = ssrc[e + 4];
    ushort4 h0 = *(const ushort4*)(feat + (size_t)s0 * D_EMB + ql * 4);
    ushort4 h1 = *(const ushort4*)(feat + (size_t)s1 * D_EMB + ql * 4);
    acc[0] += a0 * b2f(h0.x) + a1 * b2f(h1.x);
    acc[1] += a0 * b2f(h0.y) + a1 * b2f(h1.y);
    acc[2] += a0 * b2f(h0.z) + a1 * b2f(h1.z);
    acc[3] += a0 * b2f(h0.w) + a1 * b2f(h1.w);
  }
  for (; e < end; e += 4) {
    float a = sExp[e];
    int s = ssrc[e];
    ushort4 h = *(const ushort4*)(feat + (size_t)s * D_EMB + ql * 4);
    acc[0] += a * b2f(h.x);
    acc[1] += a * b2f(h.y);
    acc[2] += a * b2f(h.z);
    acc[3] += a * b2f(h.w);
  }
#pragma unroll
  for (int k = 0; k < 4; k++) {
    acc[k] += __shfl_xor(acc[k], 16, 64);
    acc[k] += __shfl_xor(acc[k], 32, 64);
  }
  if (q == 0) {
    float se = sumE[node];
    float inv = (se > 0.f) ? 1.f / se : 0.f;
    ushort4 o;
    o.x = f2b(acc[0] * inv); o.y = f2b(acc[1] * inv);
    o.z = f2b(acc[2] * inv); o.w = f2b(acc[3] * inv);
    *(ushort4*)(out + (size_t)node * D_EMB + ql * 4) = o;
  }
}

extern "C" void kernel_launch(void* const* d_in, const int* in_sizes, int n_in,
                              void* d_out, int out_size, void* d_ws,
                              size_t ws_size, hipStream_t stream) {
  const float* x = (const float*)d_in[0];
  const float* W1 = (const float*)d_in[1];
  const float* a1s = (const float*)d_in[2];
  const float* a1d = (const float*)d_in[3];
  const float* W2 = (const float*)d_in[4];
  const int* ge = (const int*)d_in[5];
  const int* esrc = ge;
  const int* edst = ge + N_EDGES;

  float* out = (float*)d_out;
  float* emb = out;                              // [N, 64]
  float* recon = out + (size_t)N_NODES * D_EMB;  // [N, 512]

  char* w = (char*)d_ws;
  ushort* h1b = (ushort*)w;    w += (size_t)N_NODES * D_LAT * 2;  // reused as decb
  ushort* interb = (ushort*)w; w += (size_t)N_NODES * D_LAT * 2;  // reused as aggEb
  ushort* embb = (ushort*)w;   w += (size_t)N_NODES * D_EMB * 2;
  ushort* W1b = (ushort*)w;    w += (size_t)D_IN * D_LAT * 2;
  ushort* W1tb = (ushort*)w;   w += (size_t)D_LAT * D_IN * 2;
  ushort* W2b = (ushort*)w;    w += (size_t)D_LAT * D_EMB * 2;
  ushort* W2tb = (ushort*)w;   w += (size_t)D_EMB * D_LAT * 2;
  float* als = (float*)w;      w += (size_t)N_NODES * 4;
  float* ald = (float*)w;      w += (size_t)N_NODES * 4;
  // counts, fillArr, sumE contiguous: one 12N-byte memset covers all three
  int* counts = (int*)w;       w += (size_t)N_NODES * 4;
  int* fillArr = (int*)w;      w += (size_t)N_NODES * 4;
  float* sumE = (float*)w;     w += (size_t)N_NODES * 4;
  int* rowptr = (int*)w;       w += (size_t)(N_NODES + 4) * 4;
  int* bsum = (int*)w;         w += 128 * 4;
  int* ssrc = (int*)w;         w += (size_t)N_EDGES * 4;
  float* sExp = (float*)w;     w += (size_t)N_EDGES * 4;

  hipMemsetAsync(counts, 0, (size_t)N_NODES * 12, stream);

  dim3 b256(256), b512(512);
  const int MB = (N_NODES + 127) / 128;  // 391

  // 0. weight conversions + edge histogram (one pass)
  conv_weights_hist<<<(N_EDGES + 255) / 256, b256, 0, stream>>>(
      W1, W2, W1b, W1tb, W2b, W2tb, edst, counts);
  // 1. h1 = x @ W1 (A f32 staged inline; BN=256 -> x read once) + fused logits
  gemm_mfma<128, 256, 2, 4, 1, 0, 1, 0, 1><<<dim3(1, MB), b512, 0, stream>>>(
      x, W1tb, (float*)nullptr, h1b, N_NODES, D_LAT, D_IN, a1s, a1d, als, ald);
  // 2-3. CSR rowptr (2-phase scan, depth 2; consumers add bsum inline)
  scan_phase1<<<SCAN_NBLK, b512, 0, stream>>>(counts, rowptr, bsum);
  scan_phase2<<<1, 128, 0, stream>>>(bsum);
  // 4. bucket edges; per-edge exp + segment denominator computed here
  scatter_kernel<<<(N_EDGES + 255) / 256, b256, 0, stream>>>(
      esrc, edst, als, ald, rowptr, bsum, fillArr, ssrc, sExp, sumE);
  // 5. inter = elu(softmax-agg of h1)  (single gather pass)
  agg_bf16_sm<<<(N_NODES + 3) / 4, b256, 0, stream>>>(
      h1b, rowptr, bsum, ssrc, sExp, sumE, interb);
  // 6. emb = inter @ W2 (f32 to d_out + bf16 copy)
  gemm_mfma<128, 64, 2, 2, 0, 1, 1, 0, 0><<<dim3(1, MB), b256, 0, stream>>>(
      interb, W2tb, emb, embb, N_NODES, D_EMB, D_LAT, nullptr, nullptr,
      nullptr, nullptr);
  // 7. aggE = softmax-agg of emb (one wave/node -> max gather TLP)
  ushort* aggEb = interb;
  agg_emb<<<(N_NODES + 3) / 4, b256, 0, stream>>>(embb, rowptr, bsum, ssrc,
                                                  sExp, sumE, aggEb);
  // 8. dec = elu(aggE @ W2^T) (ELU fused) -> reuse h1b
  ushort* decb = h1b;
  gemm_mfma<128, 256, 2, 4, 0, 0, 1, 1, 0><<<dim3(1, MB), b512, 0, stream>>>(
      aggEb, W2b, (float*)nullptr, decb, N_NODES, D_LAT, D_EMB, nullptr,
      nullptr, nullptr, nullptr);
  // 9. recon = dec @ W1^T (f32 to d_out)
  gemm_mfma<128, 256, 2, 4, 0, 1, 0, 0, 0><<<dim3(D_IN / 256, MB), b512, 0,
                                              stream>>>(
      decb, W1b, recon, (ushort*)nullptr, N_NODES, D_IN, D_LAT, nullptr,
      nullptr, nullptr, nullptr);
}

// Round 17
// 278.938 us; speedup vs baseline: 1.1129x; 1.1129x over previous
//
#include <hip/hip_runtime.h>
#include <math.h>

#define N_NODES 50000
#define N_EDGES 800000
#define D_IN 512
#define D_LAT 256
#define D_EMB 64
#define NEG_SLOPE 0.2f

typedef __attribute__((ext_vector_type(8))) short bf16x8;
typedef __attribute__((ext_vector_type(8))) unsigned short u16x8;
typedef __attribute__((ext_vector_type(4))) float f32x4;

__device__ __forceinline__ ushort f2b(float f) {
  union { float f; unsigned u; } v; v.f = f;
  return (ushort)((v.u + 0x7fffu + ((v.u >> 16) & 1u)) >> 16);
}
__device__ __forceinline__ float b2f(ushort h) {
  union { unsigned u; float f; } v; v.u = ((unsigned)h) << 16;
  return v.f;
}

__device__ __forceinline__ float wave_reduce_sum(float v) {
#pragma unroll
  for (int off = 32; off > 0; off >>= 1) v += __shfl_xor(v, off, 64);
  return v;
}

// ---------------------------------------------------------------------------
// bf16 MFMA GEMM: C[M,N] = A[M,K] @ B[N,K]^T  (row-major).
// AF32=1: A f32, staged regs+cvt+ds_write (linear LDS layout).
// AF32=0: A bf16 via global_load_lds w16.  ELU: fused elu epilogue.
// LOGIT=1 (requires grid.x==1, BN==N): also emit als/ald = C·a_src / C·a_dst.
// LDS tiles [rows][32] (64B rows): fragment reads tile 1KB.
// ---------------------------------------------------------------------------
template <int BM, int BN, int WR, int WC, int AF32, int WF32, int WBF16,
          int ELU, int LOGIT>
__global__ __launch_bounds__(WR * WC * 64) void gemm_mfma(
    const void* __restrict__ Aptr, const ushort* __restrict__ B,
    float* __restrict__ Cf, ushort* __restrict__ Cb, int M, int N, int K,
    const float* __restrict__ a_src, const float* __restrict__ a_dst,
    float* __restrict__ als, float* __restrict__ ald) {
  constexpr int BK = 32;
  constexpr int WTM = BM / WR, WTN = BN / WC;
  constexpr int FM = WTM / 16, FN = WTN / 16;
  constexpr int NT = WR * WC * 64;
  constexpr int AIT = (BM * BK * 2) / (NT * 16);
  constexpr int BIT_ = (BN * BK * 2) / (NT * 16);
  __shared__ ushort As[BM][BK];
  __shared__ ushort Bs[BN][BK];
  const int tid = threadIdx.x, lane = tid & 63, wid = tid >> 6;
  const int wr = wid / WC, wc = wid % WC;
  const int bm = blockIdx.y * BM, bn = blockIdx.x * BN;
  f32x4 acc[FM][FN] = {};

  for (int k0 = 0; k0 < K; k0 += BK) {
    if constexpr (AF32) {
      const float* Af = (const float*)Aptr;
#pragma unroll
      for (int it = 0; it < AIT; ++it) {
        int off = it * (NT * 16) + tid * 16;  // byte offset in bf16 tile
        int row = off >> 6;                   // 64 B per LDS row
        int ecol = (off & 63) >> 1;           // element col (x8)
        int grow = bm + row; grow = grow < M ? grow : (M - 1);
        const float* g = Af + (size_t)grow * K + k0 + ecol;
        float4 f0 = *(const float4*)g;
        float4 f1 = *(const float4*)(g + 4);
        u16x8 hb;
        hb[0] = f2b(f0.x); hb[1] = f2b(f0.y); hb[2] = f2b(f0.z); hb[3] = f2b(f0.w);
        hb[4] = f2b(f1.x); hb[5] = f2b(f1.y); hb[6] = f2b(f1.z); hb[7] = f2b(f1.w);
        *(u16x8*)((char*)&As[0][0] + off) = hb;
      }
    } else {
      const ushort* Ab = (const ushort*)Aptr;
#pragma unroll
      for (int it = 0; it < AIT; ++it) {
        int off = it * (NT * 16) + tid * 16;
        int row = off >> 6;
        int grow = bm + row; grow = grow < M ? grow : (M - 1);
        const ushort* g = Ab + (size_t)grow * K + k0 + ((off & 63) >> 1);
        __builtin_amdgcn_global_load_lds(
            (const __attribute__((address_space(1))) void*)g,
            (__attribute__((address_space(3))) void*)((char*)&As[0][0] + off),
            16, 0, 0);
      }
    }
#pragma unroll
    for (int it = 0; it < BIT_; ++it) {
      int off = it * (NT * 16) + tid * 16;
      int row = off >> 6;
      const ushort* g = B + (size_t)(bn + row) * K + k0 + ((off & 63) >> 1);
      __builtin_amdgcn_global_load_lds(
          (const __attribute__((address_space(1))) void*)g,
          (__attribute__((address_space(3))) void*)((char*)&Bs[0][0] + off),
          16, 0, 0);
    }
    __syncthreads();
    const int kb = (lane >> 4) * 8, rl = lane & 15;
    bf16x8 af[FM], bfr[FN];
#pragma unroll
    for (int i = 0; i < FM; ++i)
      af[i] = *(const bf16x8*)&As[wr * WTM + i * 16 + rl][kb];
#pragma unroll
    for (int j = 0; j < FN; ++j)
      bfr[j] = *(const bf16x8*)&Bs[wc * WTN + j * 16 + rl][kb];
#pragma unroll
    for (int i = 0; i < FM; ++i)
#pragma unroll
      for (int j = 0; j < FN; ++j)
        acc[i][j] = __builtin_amdgcn_mfma_f32_16x16x32_bf16(af[i], bfr[j],
                                                            acc[i][j], 0, 0, 0);
    __syncthreads();
  }
  // epilogue: C/D layout col=lane&15, row=(lane>>4)*4+reg (m89-verified)
  const int cl = lane & 15, rg = (lane >> 4) * 4;
#pragma unroll
  for (int i = 0; i < FM; ++i)
#pragma unroll
    for (int j = 0; j < FN; ++j)
#pragma unroll
      for (int r = 0; r < 4; ++r) {
        int grow = bm + wr * WTM + i * 16 + rg + r;
        if (grow >= M) continue;
        int gcol = bn + wc * WTN + j * 16 + cl;
        float v = acc[i][j][r];
        if (ELU) v = v > 0.f ? v : __expf(v) - 1.f;
        if (WF32) Cf[(size_t)grow * N + gcol] = v;
        if (WBF16) Cb[(size_t)grow * N + gcol] = f2b(v);
      }
  if constexpr (LOGIT) {
    __shared__ float alsP[BM], aldP[BM];
    for (int t = tid; t < BM; t += NT) { alsP[t] = 0.f; aldP[t] = 0.f; }
    __syncthreads();
    float asv[FN], adv[FN];
#pragma unroll
    for (int j = 0; j < FN; ++j) {
      int col = bn + wc * WTN + j * 16 + cl;
      asv[j] = a_src[col];
      adv[j] = a_dst[col];
    }
#pragma unroll
    for (int i = 0; i < FM; ++i)
#pragma unroll
      for (int r = 0; r < 4; ++r) {
        float s = 0.f, d = 0.f;
#pragma unroll
        for (int j = 0; j < FN; ++j) {
          s += acc[i][j][r] * asv[j];
          d += acc[i][j][r] * adv[j];
        }
#pragma unroll
        for (int off = 1; off < 16; off <<= 1) {
          s += __shfl_xor(s, off, 64);
          d += __shfl_xor(d, off, 64);
        }
        if (cl == 0) {
          int row = wr * WTM + i * 16 + rg + r;
          atomicAdd(&alsP[row], s);
          atomicAdd(&aldP[row], d);
        }
      }
    __syncthreads();
    for (int t = tid; t < BM; t += NT) {
      int gr = bm + t;
      if (gr < M) { als[gr] = alsP[t]; ald[gr] = aldP[t]; }
    }
  }
}

// weights conv (i < 512*256) + edge histogram (i < N_EDGES), one pass
__global__ __launch_bounds__(256) void conv_weights_hist(
    const float* __restrict__ W1, const float* __restrict__ W2,
    ushort* __restrict__ W1b, ushort* __restrict__ W1tb,
    ushort* __restrict__ W2b, ushort* __restrict__ W2tb,
    const int* __restrict__ dst, int* __restrict__ counts) {
  int i = blockIdx.x * blockDim.x + threadIdx.x;
  if (i < D_IN * D_LAT) {
    ushort b = f2b(W1[i]);
    int r = i / D_LAT, c = i % D_LAT;
    W1b[i] = b;
    W1tb[(size_t)c * D_IN + r] = b;
  }
  if (i < D_LAT * D_EMB) {
    ushort b = f2b(W2[i]);
    int r = i / D_EMB, c = i % D_EMB;
    W2b[i] = b;
    W2tb[(size_t)c * D_LAT + r] = b;
  }
  if (i < N_EDGES) atomicAdd(&counts[dst[i]], 1);
}

// --------- hierarchical exclusive scan (2-phase; consumers add bsum) -------
#define SCAN_NBLK ((N_NODES + 511) / 512)

__global__ __launch_bounds__(512) void scan_phase1(
    const int* __restrict__ counts, int* __restrict__ rowptr,
    int* __restrict__ bsum) {
  __shared__ int wsum[9];
  int idx = blockIdx.x * 512 + threadIdx.x;
  int lane = threadIdx.x & 63, wv = threadIdx.x >> 6;
  int c = (idx < N_NODES) ? counts[idx] : 0;
  int v = c;
#pragma unroll
  for (int off = 1; off < 64; off <<= 1) {
    int t = __shfl_up(v, off, 64);
    if (lane >= off) v += t;
  }
  if (lane == 63) wsum[wv] = v;
  __syncthreads();
  if (threadIdx.x == 0) {
    int r = 0;
    for (int i = 0; i < 8; i++) { int t = wsum[i]; wsum[i] = r; r += t; }
    bsum[blockIdx.x] = r;
  }
  __syncthreads();
  if (idx < N_NODES) rowptr[idx] = wsum[wv] + v - c;  // block-local exclusive
}

__global__ __launch_bounds__(128) void scan_phase2(int* __restrict__ bsum) {
  __shared__ int s[128];
  int tid = threadIdx.x;
  int v = (tid < SCAN_NBLK) ? bsum[tid] : 0;
  s[tid] = v;
  __syncthreads();
  for (int off = 1; off < 128; off <<= 1) {
    int t = (tid >= off) ? s[tid - off] : 0;
    __syncthreads();
    s[tid] += t;
    __syncthreads();
  }
  if (tid < SCAN_NBLK) bsum[tid] = s[tid] - v;  // exclusive
}

__device__ __forceinline__ int grp(const int* rowptr, const int* bsum,
                                   int idx) {
  return rowptr[idx] + bsum[idx >> 9];
}
__device__ __forceinline__ int grp_end(const int* rowptr, const int* bsum,
                                       int node) {
  return (node + 1 < N_NODES) ? rowptr[node + 1] + bsum[(node + 1) >> 9]
                              : N_EDGES;
}

// bucket edges; exp(leaky_relu(logit)) computed ONCE here and stored.
// Single int atomic per edge (round-16's extra f32 sumE atomic was 18->83us).
__global__ void scatter_kernel(const int* __restrict__ src,
                               const int* __restrict__ dst,
                               const float* __restrict__ als,
                               const float* __restrict__ ald,
                               const int* __restrict__ rowptr,
                               const int* __restrict__ bsum,
                               int* __restrict__ fillArr,
                               int* __restrict__ ssrc,
                               float* __restrict__ sExp) {
  int e = blockIdx.x * blockDim.x + threadIdx.x;
  if (e >= N_EDGES) return;
  int s = src[e], d = dst[e];
  int pos = grp(rowptr, bsum, d) + atomicAdd(&fillArr[d], 1);
  float x = als[s] + ald[d];
  x = (x > 0.f) ? x : NEG_SLOPE * x;
  sExp[pos] = __expf(x);  // fixed-shift softmax: logits ~|8|, f32-safe
  ssrc[pos] = s;
}

// agg1: pass1 = coalesced sum of sExp (no transcendentals); pass2 = gather
// with sExp weights, half-wave per edge (32 lanes x ushort8 = 512B row),
// 4 edges in flight; normalize + elu at the end. inv persisted for agg_emb.
__global__ __launch_bounds__(256) void agg_bf16_sm(
    const ushort* __restrict__ feat, const int* __restrict__ rowptr,
    const int* __restrict__ bsum, const int* __restrict__ ssrc,
    const float* __restrict__ sExp, float* __restrict__ invOut,
    ushort* __restrict__ out) {
  int wave = threadIdx.x >> 6, lane = threadIdx.x & 63;
  int node = blockIdx.x * 4 + wave;
  if (node >= N_NODES) return;
  int beg = grp(rowptr, bsum, node), end = grp_end(rowptr, bsum, node);
  float s = 0.f;
  for (int e = beg + lane; e < end; e += 64) s += sExp[e];
  s = wave_reduce_sum(s);
  float inv = (s > 0.f) ? 1.f / s : 0.f;
  if (lane == 0) invOut[node] = inv;

  int half = lane >> 5, hl = lane & 31;
  float acc[8] = {};
  int e = beg + half;
  for (; e + 6 < end; e += 8) {  // 4 edges per half-wave in flight
    int s0 = ssrc[e], s1 = ssrc[e + 2], s2 = ssrc[e + 4], s3 = ssrc[e + 6];
    float e0 = sExp[e], e1 = sExp[e + 2], e2 = sExp[e + 4], e3 = sExp[e + 6];
    u16x8 h0 = *(const u16x8*)(feat + (size_t)s0 * D_LAT + hl * 8);
    u16x8 h1 = *(const u16x8*)(feat + (size_t)s1 * D_LAT + hl * 8);
    u16x8 h2 = *(const u16x8*)(feat + (size_t)s2 * D_LAT + hl * 8);
    u16x8 h3 = *(const u16x8*)(feat + (size_t)s3 * D_LAT + hl * 8);
#pragma unroll
    for (int q = 0; q < 8; q++) acc[q] += e0 * b2f(h0[q]);
#pragma unroll
    for (int q = 0; q < 8; q++) acc[q] += e1 * b2f(h1[q]);
#pragma unroll
    for (int q = 0; q < 8; q++) acc[q] += e2 * b2f(h2[q]);
#pragma unroll
    for (int q = 0; q < 8; q++) acc[q] += e3 * b2f(h3[q]);
  }
  for (; e < end; e += 2) {
    float ev = sExp[e];
    int s2 = ssrc[e];
    u16x8 h = *(const u16x8*)(feat + (size_t)s2 * D_LAT + hl * 8);
#pragma unroll
    for (int q = 0; q < 8; q++) acc[q] += ev * b2f(h[q]);
  }
#pragma unroll
  for (int q = 0; q < 8; q++) acc[q] += __shfl_xor(acc[q], 32, 64);
  if (half == 0) {
    u16x8 o;
#pragma unroll
    for (int q = 0; q < 8; q++) {
      float v = acc[q] * inv;
      o[q] = f2b(v > 0.f ? v : __expf(v) - 1.f);
    }
    *(u16x8*)(out + (size_t)node * D_LAT + hl * 8) = o;
  }
}

// weighted gather over 64-dim bf16 rows (no elu — fused into next GEMM).
// One wave per node; quarter-waves (16 lanes x ushort4 = 128B row), 2-unroll.
__global__ __launch_bounds__(256) void agg_emb(
    const ushort* __restrict__ feat, const int* __restrict__ rowptr,
    const int* __restrict__ bsum, const int* __restrict__ ssrc,
    const float* __restrict__ sExp, const float* __restrict__ invArr,
    ushort* __restrict__ out) {
  int wave = threadIdx.x >> 6, lane = threadIdx.x & 63;
  int node = blockIdx.x * 4 + wave;
  if (node >= N_NODES) return;
  int beg = grp(rowptr, bsum, node), end = grp_end(rowptr, bsum, node);
  int q = lane >> 4, ql = lane & 15;
  float acc[4] = {};
  int e = beg + q;
  for (; e + 4 < end; e += 8) {  // 2 edges per quarter-wave in flight
    float a0 = sExp[e], a1 = sExp[e + 4];
    int s0 = ssrc[e], s1 = ssrc[e + 4];
    ushort4 h0 = *(const ushort4*)(feat + (size_t)s0 * D_EMB + ql * 4);
    ushort4 h1 = *(const ushort4*)(feat + (size_t)s1 * D_EMB + ql * 4);
    acc[0] += a0 * b2f(h0.x) + a1 * b2f(h1.x);
    acc[1] += a0 * b2f(h0.y) + a1 * b2f(h1.y);
    acc[2] += a0 * b2f(h0.z) + a1 * b2f(h1.z);
    acc[3] += a0 * b2f(h0.w) + a1 * b2f(h1.w);
  }
  for (; e < end; e += 4) {
    float a = sExp[e];
    int s = ssrc[e];
    ushort4 h = *(const ushort4*)(feat + (size_t)s * D_EMB + ql * 4);
    acc[0] += a * b2f(h.x);
    acc[1] += a * b2f(h.y);
    acc[2] += a * b2f(h.z);
    acc[3] += a * b2f(h.w);
  }
#pragma unroll
  for (int k = 0; k < 4; k++) {
    acc[k] += __shfl_xor(acc[k], 16, 64);
    acc[k] += __shfl_xor(acc[k], 32, 64);
  }
  if (q == 0) {
    float inv = invArr[node];
    ushort4 o;
    o.x = f2b(acc[0] * inv); o.y = f2b(acc[1] * inv);
    o.z = f2b(acc[2] * inv); o.w = f2b(acc[3] * inv);
    *(ushort4*)(out + (size_t)node * D_EMB + ql * 4) = o;
  }
}

extern "C" void kernel_launch(void* const* d_in, const int* in_sizes, int n_in,
                              void* d_out, int out_size, void* d_ws,
                              size_t ws_size, hipStream_t stream) {
  const float* x = (const float*)d_in[0];
  const float* W1 = (const float*)d_in[1];
  const float* a1s = (const float*)d_in[2];
  const float* a1d = (const float*)d_in[3];
  const float* W2 = (const float*)d_in[4];
  const int* ge = (const int*)d_in[5];
  const int* esrc = ge;
  const int* edst = ge + N_EDGES;

  float* out = (float*)d_out;
  float* emb = out;                              // [N, 64]
  float* recon = out + (size_t)N_NODES * D_EMB;  // [N, 512]

  char* w = (char*)d_ws;
  ushort* h1b = (ushort*)w;    w += (size_t)N_NODES * D_LAT * 2;  // reused as decb
  ushort* interb = (ushort*)w; w += (size_t)N_NODES * D_LAT * 2;  // reused as aggEb
  ushort* embb = (ushort*)w;   w += (size_t)N_NODES * D_EMB * 2;
  ushort* W1b = (ushort*)w;    w += (size_t)D_IN * D_LAT * 2;
  ushort* W1tb = (ushort*)w;   w += (size_t)D_LAT * D_IN * 2;
  ushort* W2b = (ushort*)w;    w += (size_t)D_LAT * D_EMB * 2;
  ushort* W2tb = (ushort*)w;   w += (size_t)D_EMB * D_LAT * 2;
  float* als = (float*)w;      w += (size_t)N_NODES * 4;
  float* ald = (float*)w;      w += (size_t)N_NODES * 4;  // reused as invArr
  // counts and fillArr contiguous: one 8N-byte memset covers both
  int* counts = (int*)w;       w += (size_t)N_NODES * 4;
  int* fillArr = (int*)w;      w += (size_t)N_NODES * 4;
  int* rowptr = (int*)w;       w += (size_t)(N_NODES + 4) * 4;
  int* bsum = (int*)w;         w += 128 * 4;
  int* ssrc = (int*)w;         w += (size_t)N_EDGES * 4;
  float* sExp = (float*)w;     w += (size_t)N_EDGES * 4;

  hipMemsetAsync(counts, 0, (size_t)N_NODES * 8, stream);

  dim3 b256(256), b512(512);
  const int MB = (N_NODES + 127) / 128;  // 391

  // 0. weight conversions + edge histogram (one pass)
  conv_weights_hist<<<(N_EDGES + 255) / 256, b256, 0, stream>>>(
      W1, W2, W1b, W1tb, W2b, W2tb, edst, counts);
  // 1. h1 = x @ W1 (A f32 staged inline; BN=256 -> x read once) + fused logits
  gemm_mfma<128, 256, 2, 4, 1, 0, 1, 0, 1><<<dim3(1, MB), b512, 0, stream>>>(
      x, W1tb, (float*)nullptr, h1b, N_NODES, D_LAT, D_IN, a1s, a1d, als, ald);
  // 2-3. CSR rowptr (2-phase scan, depth 2; consumers add bsum inline)
  scan_phase1<<<SCAN_NBLK, b512, 0, stream>>>(counts, rowptr, bsum);
  scan_phase2<<<1, 128, 0, stream>>>(bsum);
  // 4. bucket edges; per-edge exp computed once and stored
  scatter_kernel<<<(N_EDGES + 255) / 256, b256, 0, stream>>>(
      esrc, edst, als, ald, rowptr, bsum, fillArr, ssrc, sExp);
  // 5. inter = elu(softmax-agg of h1); inv persisted for agg_emb
  float* invArr = ald;  // ald dead after scatter
  agg_bf16_sm<<<(N_NODES + 3) / 4, b256, 0, stream>>>(
      h1b, rowptr, bsum, ssrc, sExp, invArr, interb);
  // 6. emb = inter @ W2 (f32 to d_out + bf16 copy)
  gemm_mfma<128, 64, 2, 2, 0, 1, 1, 0, 0><<<dim3(1, MB), b256, 0, stream>>>(
      interb, W2tb, emb, embb, N_NODES, D_EMB, D_LAT, nullptr, nullptr,
      nullptr, nullptr);
  // 7. aggE = softmax-agg of emb (one wave/node -> max gather TLP)
  ushort* aggEb = interb;
  agg_emb<<<(N_NODES + 3) / 4, b256, 0, stream>>>(embb, rowptr, bsum, ssrc,
                                                  sExp, invArr, aggEb);
  // 8. dec = elu(aggE @ W2^T) (ELU fused) -> reuse h1b
  ushort* decb = h1b;
  gemm_mfma<128, 256, 2, 4, 0, 0, 1, 1, 0><<<dim3(1, MB), b512, 0, stream>>>(
      aggEb, W2b, (float*)nullptr, decb, N_NODES, D_LAT, D_EMB, nullptr,
      nullptr, nullptr, nullptr);
  // 9. recon = dec @ W1^T (f32 to d_out)
  gemm_mfma<128, 256, 2, 4, 0, 1, 0, 0, 0><<<dim3(D_IN / 256, MB), b512, 0,
                                              stream>>>(
      decb, W1b, recon, (ushort*)nullptr, N_NODES, D_IN, D_LAT, nullptr,
      nullptr, nullptr, nullptr);
}

// Round 19
// 277.693 us; speedup vs baseline: 1.1179x; 1.0045x over previous
//
#include <hip/hip_runtime.h>
#include <math.h>

#define N_NODES 50000
#define N_EDGES 800000
#define D_IN 512
#define D_LAT 256
#define D_EMB 64
#define NEG_SLOPE 0.2f

typedef __attribute__((ext_vector_type(8))) short bf16x8;
typedef __attribute__((ext_vector_type(8))) unsigned short u16x8;
typedef __attribute__((ext_vector_type(4))) float f32x4;

__device__ __forceinline__ ushort f2b(float f) {
  union { float f; unsigned u; } v; v.f = f;
  return (ushort)((v.u + 0x7fffu + ((v.u >> 16) & 1u)) >> 16);
}
__device__ __forceinline__ float b2f(ushort h) {
  union { unsigned u; float f; } v; v.u = ((unsigned)h) << 16;
  return v.f;
}

// ---------------------------------------------------------------------------
// bf16 MFMA GEMM: C[M,N] = A[M,K] @ B[N,K]^T  (row-major).
// AF32=1: A f32, staged regs+cvt+ds_write (linear LDS layout).
// AF32=0: A bf16 via global_load_lds w16.  ELU: fused elu epilogue.
// LOGIT=1 (requires grid.x==1, BN==N): also emit als/ald = C·a_src / C·a_dst.
// LDS tiles [rows][32] (64B rows): fragment reads tile 1KB.
// ---------------------------------------------------------------------------
template <int BM, int BN, int WR, int WC, int AF32, int WF32, int WBF16,
          int ELU, int LOGIT>
__global__ __launch_bounds__(WR * WC * 64) void gemm_mfma(
    const void* __restrict__ Aptr, const ushort* __restrict__ B,
    float* __restrict__ Cf, ushort* __restrict__ Cb, int M, int N, int K,
    const float* __restrict__ a_src, const float* __restrict__ a_dst,
    float* __restrict__ als, float* __restrict__ ald) {
  constexpr int BK = 32;
  constexpr int WTM = BM / WR, WTN = BN / WC;
  constexpr int FM = WTM / 16, FN = WTN / 16;
  constexpr int NT = WR * WC * 64;
  constexpr int AIT = (BM * BK * 2) / (NT * 16);
  constexpr int BIT_ = (BN * BK * 2) / (NT * 16);
  __shared__ ushort As[BM][BK];
  __shared__ ushort Bs[BN][BK];
  const int tid = threadIdx.x, lane = tid & 63, wid = tid >> 6;
  const int wr = wid / WC, wc = wid % WC;
  const int bm = blockIdx.y * BM, bn = blockIdx.x * BN;
  f32x4 acc[FM][FN] = {};

  for (int k0 = 0; k0 < K; k0 += BK) {
    if constexpr (AF32) {
      const float* Af = (const float*)Aptr;
#pragma unroll
      for (int it = 0; it < AIT; ++it) {
        int off = it * (NT * 16) + tid * 16;  // byte offset in bf16 tile
        int row = off >> 6;                   // 64 B per LDS row
        int ecol = (off & 63) >> 1;           // element col (x8)
        int grow = bm + row; grow = grow < M ? grow : (M - 1);
        const float* g = Af + (size_t)grow * K + k0 + ecol;
        float4 f0 = *(const float4*)g;
        float4 f1 = *(const float4*)(g + 4);
        u16x8 hb;
        hb[0] = f2b(f0.x); hb[1] = f2b(f0.y); hb[2] = f2b(f0.z); hb[3] = f2b(f0.w);
        hb[4] = f2b(f1.x); hb[5] = f2b(f1.y); hb[6] = f2b(f1.z); hb[7] = f2b(f1.w);
        *(u16x8*)((char*)&As[0][0] + off) = hb;
      }
    } else {
      const ushort* Ab = (const ushort*)Aptr;
#pragma unroll
      for (int it = 0; it < AIT; ++it) {
        int off = it * (NT * 16) + tid * 16;
        int row = off >> 6;
        int grow = bm + row; grow = grow < M ? grow : (M - 1);
        const ushort* g = Ab + (size_t)grow * K + k0 + ((off & 63) >> 1);
        __builtin_amdgcn_global_load_lds(
            (const __attribute__((address_space(1))) void*)g,
            (__attribute__((address_space(3))) void*)((char*)&As[0][0] + off),
            16, 0, 0);
      }
    }
#pragma unroll
    for (int it = 0; it < BIT_; ++it) {
      int off = it * (NT * 16) + tid * 16;
      int row = off >> 6;
      const ushort* g = B + (size_t)(bn + row) * K + k0 + ((off & 63) >> 1);
      __builtin_amdgcn_global_load_lds(
          (const __attribute__((address_space(1))) void*)g,
          (__attribute__((address_space(3))) void*)((char*)&Bs[0][0] + off),
          16, 0, 0);
    }
    __syncthreads();
    const int kb = (lane >> 4) * 8, rl = lane & 15;
    bf16x8 af[FM], bfr[FN];
#pragma unroll
    for (int i = 0; i < FM; ++i)
      af[i] = *(const bf16x8*)&As[wr * WTM + i * 16 + rl][kb];
#pragma unroll
    for (int j = 0; j < FN; ++j)
      bfr[j] = *(const bf16x8*)&Bs[wc * WTN + j * 16 + rl][kb];
#pragma unroll
    for (int i = 0; i < FM; ++i)
#pragma unroll
      for (int j = 0; j < FN; ++j)
        acc[i][j] = __builtin_amdgcn_mfma_f32_16x16x32_bf16(af[i], bfr[j],
                                                            acc[i][j], 0, 0, 0);
    __syncthreads();
  }
  // epilogue: C/D layout col=lane&15, row=(lane>>4)*4+reg (m89-verified)
  const int cl = lane & 15, rg = (lane >> 4) * 4;
#pragma unroll
  for (int i = 0; i < FM; ++i)
#pragma unroll
    for (int j = 0; j < FN; ++j)
#pragma unroll
      for (int r = 0; r < 4; ++r) {
        int grow = bm + wr * WTM + i * 16 + rg + r;
        if (grow >= M) continue;
        int gcol = bn + wc * WTN + j * 16 + cl;
        float v = acc[i][j][r];
        if (ELU) v = v > 0.f ? v : __expf(v) - 1.f;
        if (WF32) Cf[(size_t)grow * N + gcol] = v;
        if (WBF16) Cb[(size_t)grow * N + gcol] = f2b(v);
      }
  if constexpr (LOGIT) {
    __shared__ float alsP[BM], aldP[BM];
    for (int t = tid; t < BM; t += NT) { alsP[t] = 0.f; aldP[t] = 0.f; }
    __syncthreads();
    float asv[FN], adv[FN];
#pragma unroll
    for (int j = 0; j < FN; ++j) {
      int col = bn + wc * WTN + j * 16 + cl;
      asv[j] = a_src[col];
      adv[j] = a_dst[col];
    }
#pragma unroll
    for (int i = 0; i < FM; ++i)
#pragma unroll
      for (int r = 0; r < 4; ++r) {
        float s = 0.f, d = 0.f;
#pragma unroll
        for (int j = 0; j < FN; ++j) {
          s += acc[i][j][r] * asv[j];
          d += acc[i][j][r] * adv[j];
        }
#pragma unroll
        for (int off = 1; off < 16; off <<= 1) {
          s += __shfl_xor(s, off, 64);
          d += __shfl_xor(d, off, 64);
        }
        if (cl == 0) {
          int row = wr * WTM + i * 16 + rg + r;
          atomicAdd(&alsP[row], s);
          atomicAdd(&aldP[row], d);
        }
      }
    __syncthreads();
    for (int t = tid; t < BM; t += NT) {
      int gr = bm + t;
      if (gr < M) { als[gr] = alsP[t]; ald[gr] = aldP[t]; }
    }
  }
}

// weights conv (i < 512*256) + edge histogram (i < N_EDGES), one pass
__global__ __launch_bounds__(256) void conv_weights_hist(
    const float* __restrict__ W1, const float* __restrict__ W2,
    ushort* __restrict__ W1b, ushort* __restrict__ W1tb,
    ushort* __restrict__ W2b, ushort* __restrict__ W2tb,
    const int* __restrict__ dst, int* __restrict__ counts) {
  int i = blockIdx.x * blockDim.x + threadIdx.x;
  if (i < D_IN * D_LAT) {
    ushort b = f2b(W1[i]);
    int r = i / D_LAT, c = i % D_LAT;
    W1b[i] = b;
    W1tb[(size_t)c * D_IN + r] = b;
  }
  if (i < D_LAT * D_EMB) {
    ushort b = f2b(W2[i]);
    int r = i / D_EMB, c = i % D_EMB;
    W2b[i] = b;
    W2tb[(size_t)c * D_LAT + r] = b;
  }
  if (i < N_EDGES) atomicAdd(&counts[dst[i]], 1);
}

// --------- hierarchical exclusive scan (2-phase; consumers add bsum) -------
#define SCAN_NBLK ((N_NODES + 511) / 512)

__global__ __launch_bounds__(512) void scan_phase1(
    const int* __restrict__ counts, int* __restrict__ rowptr,
    int* __restrict__ bsum) {
  __shared__ int wsum[9];
  int idx = blockIdx.x * 512 + threadIdx.x;
  int lane = threadIdx.x & 63, wv = threadIdx.x >> 6;
  int c = (idx < N_NODES) ? counts[idx] : 0;
  int v = c;
#pragma unroll
  for (int off = 1; off < 64; off <<= 1) {
    int t = __shfl_up(v, off, 64);
    if (lane >= off) v += t;
  }
  if (lane == 63) wsum[wv] = v;
  __syncthreads();
  if (threadIdx.x == 0) {
    int r = 0;
    for (int i = 0; i < 8; i++) { int t = wsum[i]; wsum[i] = r; r += t; }
    bsum[blockIdx.x] = r;
  }
  __syncthreads();
  if (idx < N_NODES) rowptr[idx] = wsum[wv] + v - c;  // block-local exclusive
}

__global__ __launch_bounds__(128) void scan_phase2(int* __restrict__ bsum) {
  __shared__ int s[128];
  int tid = threadIdx.x;
  int v = (tid < SCAN_NBLK) ? bsum[tid] : 0;
  s[tid] = v;
  __syncthreads();
  for (int off = 1; off < 128; off <<= 1) {
    int t = (tid >= off) ? s[tid - off] : 0;
    __syncthreads();
    s[tid] += t;
    __syncthreads();
  }
  if (tid < SCAN_NBLK) bsum[tid] = s[tid] - v;  // exclusive
}

__device__ __forceinline__ int grp(const int* rowptr, const int* bsum,
                                   int idx) {
  return rowptr[idx] + bsum[idx >> 9];
}
__device__ __forceinline__ int grp_end(const int* rowptr, const int* bsum,
                                       int node) {
  return (node + 1 < N_NODES) ? rowptr[node + 1] + bsum[(node + 1) >> 9]
                              : N_EDGES;
}

// bucket edges; exp(leaky_relu(logit)) computed ONCE here and stored.
// Single int atomic per edge (round-16's extra f32 sumE atomic was 18->83us).
__global__ void scatter_kernel(const int* __restrict__ src,
                               const int* __restrict__ dst,
                               const float* __restrict__ als,
                               const float* __restrict__ ald,
                               const int* __restrict__ rowptr,
                               const int* __restrict__ bsum,
                               int* __restrict__ fillArr,
                               int* __restrict__ ssrc,
                               float* __restrict__ sExp) {
  int e = blockIdx.x * blockDim.x + threadIdx.x;
  if (e >= N_EDGES) return;
  int s = src[e], d = dst[e];
  int pos = grp(rowptr, bsum, d) + atomicAdd(&fillArr[d], 1);
  float x = als[s] + ald[d];
  x = (x > 0.f) ? x : NEG_SLOPE * x;
  sExp[pos] = __expf(x);  // fixed-shift softmax: logits ~|8|, f32-safe
  ssrc[pos] = s;
}

// agg1: SINGLE pass with deferred normalization — gather acc = sum e*h and
// ssum = sum e in the same loop (ssum replicated across a half-wave's 32
// lanes); combine halves via shfl_xor(32); scale by 1/ssum + elu at the end.
// Half-wave per edge (32 lanes x ushort8 = 512B row), 4 edges in flight.
__global__ __launch_bounds__(256) void agg_bf16_sm(
    const ushort* __restrict__ feat, const int* __restrict__ rowptr,
    const int* __restrict__ bsum, const int* __restrict__ ssrc,
    const float* __restrict__ sExp, ushort* __restrict__ out) {
  int wave = threadIdx.x >> 6, lane = threadIdx.x & 63;
  int node = blockIdx.x * 4 + wave;
  if (node >= N_NODES) return;
  int beg = grp(rowptr, bsum, node), end = grp_end(rowptr, bsum, node);

  int half = lane >> 5, hl = lane & 31;
  float acc[8] = {};
  float ssum = 0.f;
  int e = beg + half;
  for (; e + 6 < end; e += 8) {  // 4 edges per half-wave in flight
    int s0 = ssrc[e], s1 = ssrc[e + 2], s2 = ssrc[e + 4], s3 = ssrc[e + 6];
    float e0 = sExp[e], e1 = sExp[e + 2], e2 = sExp[e + 4], e3 = sExp[e + 6];
    u16x8 h0 = *(const u16x8*)(feat + (size_t)s0 * D_LAT + hl * 8);
    u16x8 h1 = *(const u16x8*)(feat + (size_t)s1 * D_LAT + hl * 8);
    u16x8 h2 = *(const u16x8*)(feat + (size_t)s2 * D_LAT + hl * 8);
    u16x8 h3 = *(const u16x8*)(feat + (size_t)s3 * D_LAT + hl * 8);
    ssum += (e0 + e1) + (e2 + e3);
#pragma unroll
    for (int q = 0; q < 8; q++) acc[q] += e0 * b2f(h0[q]);
#pragma unroll
    for (int q = 0; q < 8; q++) acc[q] += e1 * b2f(h1[q]);
#pragma unroll
    for (int q = 0; q < 8; q++) acc[q] += e2 * b2f(h2[q]);
#pragma unroll
    for (int q = 0; q < 8; q++) acc[q] += e3 * b2f(h3[q]);
  }
  for (; e < end; e += 2) {
    float ev = sExp[e];
    int s2 = ssrc[e];
    ssum += ev;
    u16x8 h = *(const u16x8*)(feat + (size_t)s2 * D_LAT + hl * 8);
#pragma unroll
    for (int q = 0; q < 8; q++) acc[q] += ev * b2f(h[q]);
  }
  ssum += __shfl_xor(ssum, 32, 64);
  float inv = (ssum > 0.f) ? 1.f / ssum : 0.f;
#pragma unroll
  for (int q = 0; q < 8; q++) acc[q] += __shfl_xor(acc[q], 32, 64);
  if (half == 0) {
    u16x8 o;
#pragma unroll
    for (int q = 0; q < 8; q++) {
      float v = acc[q] * inv;
      o[q] = f2b(v > 0.f ? v : __expf(v) - 1.f);
    }
    *(u16x8*)(out + (size_t)node * D_LAT + hl * 8) = o;
  }
}

// agg over 64-dim bf16 rows, same deferred-normalization trick (quarter-wave
// partial sums; shfl_xor 16+32). No elu — fused into the next GEMM.
__global__ __launch_bounds__(256) void agg_emb(
    const ushort* __restrict__ feat, const int* __restrict__ rowptr,
    const int* __restrict__ bsum, const int* __restrict__ ssrc,
    const float* __restrict__ sExp, ushort* __restrict__ out) {
  int wave = threadIdx.x >> 6, lane = threadIdx.x & 63;
  int node = blockIdx.x * 4 + wave;
  if (node >= N_NODES) return;
  int beg = grp(rowptr, bsum, node), end = grp_end(rowptr, bsum, node);
  int q = lane >> 4, ql = lane & 15;
  float acc[4] = {};
  float ssum = 0.f;
  int e = beg + q;
  for (; e + 4 < end; e += 8) {  // 2 edges per quarter-wave in flight
    float a0 = sExp[e], a1 = sExp[e + 4];
    int s0 = ssrc[e], s1 = ssrc[e + 4];
    ushort4 h0 = *(const ushort4*)(feat + (size_t)s0 * D_EMB + ql * 4);
    ushort4 h1 = *(const ushort4*)(feat + (size_t)s1 * D_EMB + ql * 4);
    ssum += a0 + a1;
    acc[0] += a0 * b2f(h0.x) + a1 * b2f(h1.x);
    acc[1] += a0 * b2f(h0.y) + a1 * b2f(h1.y);
    acc[2] += a0 * b2f(h0.z) + a1 * b2f(h1.z);
    acc[3] += a0 * b2f(h0.w) + a1 * b2f(h1.w);
  }
  for (; e < end; e += 4) {
    float a = sExp[e];
    int s = ssrc[e];
    ssum += a;
    ushort4 h = *(const ushort4*)(feat + (size_t)s * D_EMB + ql * 4);
    acc[0] += a * b2f(h.x);
    acc[1] += a * b2f(h.y);
    acc[2] += a * b2f(h.z);
    acc[3] += a * b2f(h.w);
  }
  ssum += __shfl_xor(ssum, 16, 64);
  ssum += __shfl_xor(ssum, 32, 64);
  float inv = (ssum > 0.f) ? 1.f / ssum : 0.f;
#pragma unroll
  for (int k = 0; k < 4; k++) {
    acc[k] += __shfl_xor(acc[k], 16, 64);
    acc[k] += __shfl_xor(acc[k], 32, 64);
  }
  if (q == 0) {
    ushort4 o;
    o.x = f2b(acc[0] * inv); o.y = f2b(acc[1] * inv);
    o.z = f2b(acc[2] * inv); o.w = f2b(acc[3] * inv);
    *(ushort4*)(out + (size_t)node * D_EMB + ql * 4) = o;
  }
}

extern "C" void kernel_launch(void* const* d_in, const int* in_sizes, int n_in,
                              void* d_out, int out_size, void* d_ws,
                              size_t ws_size, hipStream_t stream) {
  const float* x = (const float*)d_in[0];
  const float* W1 = (const float*)d_in[1];
  const float* a1s = (const float*)d_in[2];
  const float* a1d = (const float*)d_in[3];
  const float* W2 = (const float*)d_in[4];
  const int* ge = (const int*)d_in[5];
  const int* esrc = ge;
  const int* edst = ge + N_EDGES;

  float* out = (float*)d_out;
  float* emb = out;                              // [N, 64]
  float* recon = out + (size_t)N_NODES * D_EMB;  // [N, 512]

  char* w = (char*)d_ws;
  ushort* h1b = (ushort*)w;    w += (size_t)N_NODES * D_LAT * 2;  // reused as decb
  ushort* interb = (ushort*)w; w += (size_t)N_NODES * D_LAT * 2;  // reused as aggEb
  ushort* embb = (ushort*)w;   w += (size_t)N_NODES * D_EMB * 2;
  ushort* W1b = (ushort*)w;    w += (size_t)D_IN * D_LAT * 2;
  ushort* W1tb = (ushort*)w;   w += (size_t)D_LAT * D_IN * 2;
  ushort* W2b = (ushort*)w;    w += (size_t)D_LAT * D_EMB * 2;
  ushort* W2tb = (ushort*)w;   w += (size_t)D_EMB * D_LAT * 2;
  float* als = (float*)w;      w += (size_t)N_NODES * 4;
  float* ald = (float*)w;      w += (size_t)N_NODES * 4;
  // counts and fillArr contiguous: one 8N-byte memset covers both
  int* counts = (int*)w;       w += (size_t)N_NODES * 4;
  int* fillArr = (int*)w;      w += (size_t)N_NODES * 4;
  int* rowptr = (int*)w;       w += (size_t)(N_NODES + 4) * 4;
  int* bsum = (int*)w;         w += 128 * 4;
  int* ssrc = (int*)w;         w += (size_t)N_EDGES * 4;
  float* sExp = (float*)w;     w += (size_t)N_EDGES * 4;

  hipMemsetAsync(counts, 0, (size_t)N_NODES * 8, stream);

  dim3 b256(256), b512(512);
  const int MB = (N_NODES + 127) / 128;  // 391

  // 0. weight conversions + edge histogram (one pass)
  conv_weights_hist<<<(N_EDGES + 255) / 256, b256, 0, stream>>>(
      W1, W2, W1b, W1tb, W2b, W2tb, edst, counts);
  // 1. h1 = x @ W1 (A f32 staged inline; BN=256 -> x read once) + fused logits
  gemm_mfma<128, 256, 2, 4, 1, 0, 1, 0, 1><<<dim3(1, MB), b512, 0, stream>>>(
      x, W1tb, (float*)nullptr, h1b, N_NODES, D_LAT, D_IN, a1s, a1d, als, ald);
  // 2-3. CSR rowptr (2-phase scan, depth 2; consumers add bsum inline)
  scan_phase1<<<SCAN_NBLK, b512, 0, stream>>>(counts, rowptr, bsum);
  scan_phase2<<<1, 128, 0, stream>>>(bsum);
  // 4. bucket edges; per-edge exp computed once and stored
  scatter_kernel<<<(N_EDGES + 255) / 256, b256, 0, stream>>>(
      esrc, edst, als, ald, rowptr, bsum, fillArr, ssrc, sExp);
  // 5. inter = elu(softmax-agg of h1)  (single pass, deferred normalization)
  agg_bf16_sm<<<(N_NODES + 3) / 4, b256, 0, stream>>>(
      h1b, rowptr, bsum, ssrc, sExp, interb);
  // 6. emb = inter @ W2 (f32 to d_out + bf16 copy)
  gemm_mfma<128, 64, 2, 2, 0, 1, 1, 0, 0><<<dim3(1, MB), b256, 0, stream>>>(
      interb, W2tb, emb, embb, N_NODES, D_EMB, D_LAT, nullptr, nullptr,
      nullptr, nullptr);
  // 7. aggE = softmax-agg of emb (one wave/node -> max gather TLP)
  ushort* aggEb = interb;
  agg_emb<<<(N_NODES + 3) / 4, b256, 0, stream>>>(embb, rowptr, bsum, ssrc,
                                                  sExp, aggEb);
  // 8. dec = elu(aggE @ W2^T) (ELU fused) -> reuse h1b
  ushort* decb = h1b;
  gemm_mfma<128, 256, 2, 4, 0, 0, 1, 1, 0><<<dim3(1, MB), b512, 0, stream>>>(
      aggEb, W2b, (float*)nullptr, decb, N_NODES, D_LAT, D_EMB, nullptr,
      nullptr, nullptr, nullptr);
  // 9. recon = dec @ W1^T (f32 to d_out)
  gemm_mfma<128, 256, 2, 4, 0, 1, 0, 0, 0><<<dim3(D_IN / 256, MB), b512, 0,
                                              stream>>>(
      decb, W1b, recon, (ushort*)nullptr, N_NODES, D_IN, D_LAT, nullptr,
      nullptr, nullptr, nullptr);
}